// Round 12
// baseline (1364.561 us; speedup 1.0000x reference)
//
#include <hip/hip_runtime.h>

typedef __attribute__((ext_vector_type(8)))  short  s16x8;
typedef __attribute__((ext_vector_type(8)))  __bf16 bf16x8;
typedef __attribute__((ext_vector_type(16))) float  f32x16;
typedef __attribute__((ext_vector_type(4)))  unsigned int u32x4;

#define EPSF 1e-36f

static __device__ __forceinline__ f32x16 MFMA(s16x8 a, s16x8 b, f32x16 c) {
  return __builtin_amdgcn_mfma_f32_32x32x16_bf16(
      __builtin_bit_cast(bf16x8, a), __builtin_bit_cast(bf16x8, b), c, 0, 0, 0);
}

static __device__ __forceinline__ short f2bf(float f) {
  unsigned u = __builtin_bit_cast(unsigned, f);
  u = (u + 0x7FFFu + ((u >> 16) & 1u)) >> 16;
  return (short)u;
}

static __device__ __forceinline__ unsigned pkf(float a, float b) {
  return (unsigned)(unsigned short)f2bf(a) | ((unsigned)(unsigned short)f2bf(b) << 16);
}

// D (C/D layout: col=lane&31, row=(reg&3)+8*(reg>>2)+4h) -> two k-chunk bf16
// operand fragments; in-register pack + half-swap via lane^32. PROVEN R6/R8/R10.
static __device__ __forceinline__ void redistR(const f32x16 d, float sc, int h,
                                               s16x8& f0, s16x8& f1) {
  unsigned pk[8];
#pragma unroll
  for (int q = 0; q < 8; ++q) pk[q] = pkf(d[2 * q] * sc, d[2 * q + 1] * sc);
  unsigned s0 = h ? pk[0] : pk[2];
  unsigned s1 = h ? pk[1] : pk[3];
  unsigned s2 = h ? pk[4] : pk[6];
  unsigned s3 = h ? pk[5] : pk[7];
  unsigned r0 = (unsigned)__shfl_xor((int)s0, 32);
  unsigned r1 = (unsigned)__shfl_xor((int)s1, 32);
  unsigned r2 = (unsigned)__shfl_xor((int)s2, 32);
  unsigned r3 = (unsigned)__shfl_xor((int)s3, 32);
  u32x4 a, b;
  a.x = h ? r0 : pk[0]; a.y = h ? r1 : pk[1]; a.z = h ? pk[2] : r0; a.w = h ? pk[3] : r1;
  b.x = h ? r2 : pk[4]; b.y = h ? r3 : pk[5]; b.z = h ? pk[6] : r2; b.w = h ? pk[7] : r3;
  f0 = __builtin_bit_cast(s16x8, a);
  f1 = __builtin_bit_cast(s16x8, b);
}

// flat step sig in [0,368): 16 groups of (big site: 16 m-steps, 7 small sites: 1 step)
static __device__ __forceinline__ void decodeStep(int sig, int& site, int& m, int& off) {
  int g = sig / 23, o = sig - g * 23;
  if (o < 16) { site = 8 * g; m = o; off = g * 376832 + o * 16384; }
  else { site = 8 * g + (o - 15); m = 0; off = g * 376832 + 262144 + (o - 16) * 16384; }
}

// ---------------- prep: embedding table Em[site][n][16] (f32) ----------------
extern "C" __global__ void prep_emb_k(const float* __restrict__ x, float* __restrict__ Em) {
  int id = blockIdx.x * 256 + threadIdx.x;
  int site = id >> 10, n = id & 1023;
  float x0 = x[(n * 128 + site) * 2 + 0];
  float x1 = x[(n * 128 + site) * 2 + 1];
  const float P5 = 1.57079632679f, P25 = 0.785398163397f, R = 0.70710678118f;
  float u[4] = {sinf(P5 * x0) * R, cosf(P5 * x0) * R, sinf(P25 * x0) * R, cosf(P25 * x0) * R};
  float v[4] = {sinf(P5 * x1) * R, cosf(P5 * x1) * R, sinf(P25 * x1) * R, cosf(P25 * x1) * R};
#pragma unroll
  for (int a = 0; a < 4; ++a) {
    float4 o;
    o.x = u[a] * v[0]; o.y = u[a] * v[1]; o.z = u[a] * v[2]; o.w = u[a] * v[3];
    *(float4*)&Em[id * 16 + a * 4] = o;
  }
}

// ---------------- prep: weights -> As [m][r][e][l] (partition) + As2 [m][l][r][e] (B-form) ----------------
extern "C" __global__ void prep_w_k(const float* __restrict__ wb, const float* __restrict__ wsm,
                                    short* __restrict__ As, short* __restrict__ As2) {
  int site = blockIdx.x;
  bool big = (site & 7) == 0;
  int nE = big ? 262144 : 16384;
  int nb = (site + 7) >> 3;
  int bs = nb * 262144 + (site - nb) * 16384;
  int kb = site >> 3;
  int ksm = site - kb - 1;
  for (int i = threadIdx.x; i < nE; i += 256) {
    int e = i & 15, r = (i >> 4) & 31, l = (i >> 9) & 31, m = i >> 14;
    float val = big ? wb[(((kb * 32 + l) * 16 + e) * 16 + m) * 32 + r]
                    : wsm[((ksm * 32 + l) * 16 + e) * 32 + r];
    if (site == 0 && l != 0) val = 0.f;
    if (site == 127 && r != 0) val = 0.f;
    short bv = f2bf(val);
    As2[bs + i] = bv;                                      // [m][l][r][e]
    As[bs + ((m * 32 + r) * 16 + e) * 32 + l] = bv;        // [m][r][e][l]
  }
}

// ---------------- main: blocks 0..255 = 4 samples (4 consumer + 4 producer waves),
//                  block 256 = partition (8 waves x 2 e) ----------------
extern "C" __global__ void __launch_bounds__(512, 1)
tn_main(const short* __restrict__ As, const short* __restrict__ As2,
        const float* __restrict__ Em, float* __restrict__ out) {
  // sample blocks: bufU [2][4][16][32] u32 = 16KB @0 (parity stride 2048 u32!),
  //                EmL [128][4][16] f32 = 32KB @16384
  // partition block: partials [2 parity][8 waves][1056 f32] = 67584 B (aliases all)
  __shared__ __align__(16) char smem[67584];
  const int tid = threadIdx.x;
  const int lane = tid & 63;
  const int w = tid >> 6;
  const int c31 = lane & 31;
  const int h = lane >> 5;
  const f32x16 Z = {0.f,0.f,0.f,0.f,0.f,0.f,0.f,0.f,0.f,0.f,0.f,0.f,0.f,0.f,0.f,0.f};

  if (blockIdx.x < 256) {
    unsigned* bufU = (unsigned*)smem;              // [parity][s][l2][r]
    float* EmL = (float*)(smem + 16384);           // [site][s][16]
    const int n0 = blockIdx.x * 4;

    // ---- stage this block's Em slice (32KB), all 8 waves ----
    {
      float4* dst = (float4*)EmL;
#pragma unroll
      for (int k = 0; k < 4; ++k) {
        int j = k * 512 + tid;                      // j = (site*4+s)*4+q
        int st = j >> 4, s = (j >> 2) & 3, q = j & 3;
        dst[j] = *((const float4*)(Em + ((size_t)st * 1024 + n0 + s) * 16) + q);
      }
    }
    __syncthreads();

    if (w < 4) {
      // ===================== CONSUMER: chain for sample n0+w =====================
      s16x8 Mf0 = {0,0,0,0,0,0,0,0}, Mf1 = {0,0,0,0,0,0,0,0};
      if (lane == 0) Mf0[0] = (short)0x3F80;       // M_init = e0 e0^T
      f32x16 Macc = Z;
      float log_norm = 0.f;

      __syncthreads();                              // producers finished B(0)
#pragma unroll 1
      for (int sig = 0; sig < 368; ++sig) {
        int site, m, off; decodeStep(sig, site, m, off); (void)off;
        const unsigned* bu = bufU + (sig & 1) * 2048 + w * 512 + c31;
        u32x4 b0v, b1v;
#pragma unroll
        for (int j = 0; j < 4; ++j) ((unsigned*)&b0v)[j] = bu[(4 * h + j) * 32];
#pragma unroll
        for (int j = 0; j < 4; ++j) ((unsigned*)&b1v)[j] = bu[(8 + 4 * h + j) * 32];
        s16x8 c0 = __builtin_bit_cast(s16x8, b0v);
        s16x8 c1 = __builtin_bit_cast(s16x8, b1v);

        f32x16 D1 = MFMA(Mf0, c0, Z);
        D1 = MFMA(Mf1, c1, D1);
        s16x8 Cf0, Cf1;
        redistR(D1, 1.f, h, Cf0, Cf1);
        if (m == 0) Macc = Z;
        Macc = MFMA(c0, Cf0, Macc);
        Macc = MFMA(c1, Cf1, Macc);

        bool lastM = (m == (((site & 7) == 0) ? 15 : 0));
        if (lastM) {
          if (site < 127) {
            float s = fabsf(Macc[0]);
#pragma unroll
            for (int j = 1; j < 16; ++j) s = fmaxf(s, fabsf(Macc[j]));
#pragma unroll
            for (int off2 = 32; off2 >= 1; off2 >>= 1) s = fmaxf(s, __shfl_xor(s, off2));
            float inv = 1.f / (s + EPSF);
            log_norm += logf(s + EPSF);
            redistR(Macc, inv, h, Mf0, Mf1);
          } else {
            if (lane == 0) out[n0 + w] = logf(fmaxf(Macc[0], 0.f) + EPSF) + log_norm;
          }
        }
        __syncthreads();                            // step boundary
      }
    } else {
      // ===================== PRODUCER: B-form via MFMA, W from global =====================
      const int pw = w - 4;                         // tiles l = 8*pw .. 8*pw+7
      s16x8 Ef = {0,0,0,0,0,0,0,0};
      int curSite = -1;
      s16x8 W0[8], W1[8];

      auto loadW = [&](int sigN, s16x8* W) {
        int st, mm, off; decodeStep(sigN, st, mm, off);
        const short* base = As2 + off + ((8 * pw) * 32 + c31) * 16 + 8 * h;
#pragma unroll
        for (int t = 0; t < 8; ++t) W[t] = *(const s16x8*)(base + t * 512);
      };

      auto produce = [&](int sigN, const s16x8* W) {
        int st, mm, off; decodeStep(sigN, st, mm, off); (void)off;
        if (mm == 0 && st != curSite) {
          curSite = st;
          float4 q0 = {0.f,0.f,0.f,0.f}, q1 = {0.f,0.f,0.f,0.f};
          if (c31 < 4) {
            const float4* ep = (const float4*)(EmL + (st * 4 + c31) * 16);
            q0 = ep[2 * h];
            q1 = ep[2 * h + 1];
          }
          u32x4 ef;
          ef.x = pkf(q0.x, q0.y); ef.y = pkf(q0.z, q0.w);
          ef.z = pkf(q1.x, q1.y); ef.w = pkf(q1.z, q1.w);
          Ef = __builtin_bit_cast(s16x8, ef);
        }
        unsigned* bw = bufU + (sigN & 1) * 2048;
#pragma unroll
        for (int u = 0; u < 4; ++u) {
          f32x16 DA = MFMA(Ef, W[2 * u], Z);
          f32x16 DB = MFMA(Ef, W[2 * u + 1], Z);
          if (h == 0) {
            const int l2 = 4 * pw + u;
#pragma unroll
            for (int q = 0; q < 4; ++q)
              bw[q * 512 + l2 * 32 + c31] = pkf(DA[q], DB[q]);
          }
        }
      };

      loadW(0, W0);
      loadW(1, W1);
      produce(0, W0);
      __syncthreads();                              // B(0) ready

#pragma unroll 1
      for (int sig = 0; sig < 368; sig += 2) {
        // iter sig (even): produce B(sig+1) from W1; prefetch W(sig+2) -> W0
        if (sig + 2 < 368) loadW(sig + 2, W0);
        produce(sig + 1, W1);
        __syncthreads();
        // iter sig+1 (odd): produce B(sig+2) from W0; prefetch W(sig+3) -> W1
        if (sig + 3 < 368) loadW(sig + 3, W1);
        if (sig + 2 < 368) produce(sig + 2, W0);
        __syncthreads();
      }
    }
  } else {
    // ===================== PARTITION (log_Z): 8 waves x 2 e (R9-proven) =====================
    float* part = (float*)smem;                     // [parity][wave][1056]
    s16x8 Mf0 = {0,0,0,0,0,0,0,0}, Mf1 = {0,0,0,0,0,0,0,0};
    if (lane == 0) Mf0[0] = (short)0x3F80;
    f32x16 Pacc = Z;
    float log_norm = 0.f;

    __syncthreads();
#pragma unroll 1
    for (int sig = 0; sig < 368; ++sig) {
      int site, m, off; decodeStep(sig, site, m, off);
      if (m == 0) Pacc = Z;
#pragma unroll
      for (int q = 0; q < 2; ++q) {
        int e = 2 * w + q;
        const short* ap = As + off + (c31 * 16 + e) * 32;
        s16x8 pa = *(const s16x8*)(ap + 8 * h);
        s16x8 pb = *(const s16x8*)(ap + 16 + 8 * h);
        f32x16 D1 = MFMA(Mf0, pa, Z);
        D1 = MFMA(Mf1, pb, D1);
        s16x8 Cf0, Cf1;
        redistR(D1, 1.f, h, Cf0, Cf1);
        Pacc = MFMA(pa, Cf0, Pacc);
        Pacc = MFMA(pb, Cf1, Pacc);
      }
      bool lastM = (m == (((site & 7) == 0) ? 15 : 0));
      if (lastM) {
        float* myr = part + ((site & 1) * 8 + w) * 1056;
#pragma unroll
        for (int reg = 0; reg < 16; ++reg) {
          int row = (reg & 3) + 8 * (reg >> 2) + 4 * h;
          myr[row * 33 + c31] = Pacc[reg];
        }
      }
      __syncthreads();                              // one barrier per sig (uniform)
      if (lastM) {
        const float* base = part + (site & 1) * 8 * 1056;
        f32x16 tot;
#pragma unroll
        for (int reg = 0; reg < 16; ++reg) {
          int row = (reg & 3) + 8 * (reg >> 2) + 4 * h;
          int idx = row * 33 + c31;
          float sum = 0.f;
#pragma unroll
          for (int w2 = 0; w2 < 8; ++w2) sum += base[w2 * 1056 + idx];
          tot[reg] = sum;
        }
        if (site < 127) {
          float s = fabsf(tot[0]);
#pragma unroll
          for (int j = 1; j < 16; ++j) s = fmaxf(s, fabsf(tot[j]));
#pragma unroll
          for (int off2 = 32; off2 >= 1; off2 >>= 1) s = fmaxf(s, __shfl_xor(s, off2));
          float inv = 1.f / (s + EPSF);
          log_norm += logf(s + EPSF);
          redistR(tot, inv, h, Mf0, Mf1);
        } else {
          if (tid == 0) out[1024] = logf(fmaxf(tot[0], 0.f) + EPSF) + log_norm;
        }
      }
    }
  }
}

extern "C" void kernel_launch(void* const* d_in, const int* in_sizes, int n_in,
                              void* d_out, int out_size, void* d_ws, size_t ws_size,
                              hipStream_t stream) {
  (void)in_sizes; (void)n_in; (void)out_size; (void)ws_size;
  const float* x   = (const float*)d_in[0];
  const float* wb  = (const float*)d_in[1];
  const float* wsm = (const float*)d_in[2];
  char* ws = (char*)d_ws;
  short* As  = (short*)ws;                         // 12,058,624 B  [m][r][e][l]
  short* As2 = (short*)(ws + 12058624);            // 12,058,624 B  [m][l][r][e]
  float* Em  = (float*)(ws + 24117248);            //  8,388,608 B
  float* out = (float*)d_out;                      // 1024 logits + log_Z

  prep_emb_k<<<512, 256, 0, stream>>>(x, Em);
  prep_w_k<<<128, 256, 0, stream>>>(wb, wsm, As, As2);
  tn_main<<<257, 512, 0, stream>>>(As, As2, Em, out);
}